// Round 12
// baseline (421.557 us; speedup 1.0000x reference)
//
#include <hip/hip_runtime.h>
#include <cstdint>
#include <cstddef>

typedef unsigned char  u8;
typedef unsigned short u16;
typedef unsigned int   u32;

typedef __attribute__((ext_vector_type(8)))  short s16x8;
typedef __attribute__((ext_vector_type(4)))  short s16x4;
typedef __attribute__((ext_vector_type(4)))  float f32x4;
typedef __attribute__((ext_vector_type(16))) float f32x16;
typedef __attribute__((ext_vector_type(4)))  u32   u32x4;

#define NTILE 2048   // 262144 / 128 rows per tile

// LDS: ACT_EQ 64KB + ACT_WK 64KB + WB 2x16KB = 160KB
#define ACT_EQ 0
#define ACT_WK 65536
#define WB0_OFF 131072
#define WBSZ    16384
#define SMEM_BYTES 163840
#define WBo(p) (WB0_OFF + (p)*WBSZ)

// XOR-swizzled layouts
#define AIDX(col, fb)  ((((col)*512) + (fb)) ^ (((col)&7) << 4))      // act [128 col][512B]
#define WIDX(row, kb)  ((((row)*256) + (kb)) ^ (((row)&15) << 4))     // wchunk [64 row][256B], 16-slot
#define EIDX2(row, kb) ((((row)*32)  + (kb)) ^ ((((row)>>2)&1) << 4)) // emb16 [256 row][32B]

#define MFMA32 __builtin_amdgcn_mfma_f32_32x32x16_bf16

// raw barrier: LDS visibility without draining vmem (prefetch survives)
#define BARX() do { __builtin_amdgcn_sched_barrier(0); \
  asm volatile("s_waitcnt lgkmcnt(0)"); \
  __builtin_amdgcn_s_barrier(); \
  __builtin_amdgcn_sched_barrier(0); } while (0)

// ---------------- workspace layout (bytes) ----------------
static const size_t PA_OFF   = 0;          // f32 [2048 tile][512 f]
static const size_t PB_OFF   = 4194304;
static const size_t QA_OFF   = 8388608;    // f32 [256 g][512 f]
static const size_t QB_OFF   = 8912896;
static const size_t MU_OFF   = 9437184;
static const size_t RSTD_OFF = 9439232;
static const size_t B1E_OFF  = 9441280;
static const size_t WEMB_OFF = 9442304;    // bf16 [3][256][16]
static const size_t WV_OFF   = 9491456;    // bf16 [256][256]
static const size_t W2_OFF   = 9622528;    // bf16 [128][256]
static const size_t W1S_OFF  = 9688064;    // bf16 [256][512]
static const size_t WU_OFF   = 9950208;    // f32 [256][256]
static const size_t G_OFF    = 10212352;   // f32 [2][256][13]
static const size_t GG_OFF   = 10238976;   // f32 [2][256]
static const size_t SCP_OFF  = 10241024;   // f32 [2][256]
static const size_t WROW_OFF = 10243072;   // f32 [262144]
static const size_t XA_OFF   = 11534336;   // pre-swizzled atten tiles [2048][65536B]
static const size_t WS_NEED_X = XA_OFF + (size_t)2048*65536;   // 145,752,064

__device__ __forceinline__ u16 f2bf(float f) {
  u32 u = __builtin_bit_cast(u32, f);
  u += 0x7FFFu + ((u >> 16) & 1u);     // RNE
  return (u16)(u >> 16);
}
__device__ __forceinline__ float bf2f(u16 h) {
  u32 u = ((u32)h) << 16;
  return __builtin_bit_cast(float, u);
}
__device__ __forceinline__ f32x16 zero16() {
  f32x16 z;
  #pragma unroll
  for (int i = 0; i < 16; ++i) z[i] = 0.f;
  return z;
}

// ---------------- K0 setup kernels ----------------
__global__ void k0_convert(const float* __restrict__ We,  const float* __restrict__ Wk1,
                           const float* __restrict__ Wk2, const float* __restrict__ Wv,
                           const float* __restrict__ W2,
                           u16* __restrict__ wEmb, u16* __restrict__ wV, u16* __restrict__ wW2)
{
  int i = blockIdx.x * 256 + threadIdx.x;
  if (i < 12288) {                          // emb16 [agent][256][16]
    int which = i >> 12, rem = i & 4095, h = rem >> 4, c = rem & 15;
    const float* W = (which == 0) ? We : (which == 1) ? Wk1 : Wk2;
    wEmb[i] = (c < 13) ? f2bf(W[h*13 + c]) : (u16)0;
  } else if (i < 12288 + 65536) {
    int j = i - 12288;
    wV[j] = f2bf(Wv[j]);
  } else if (i < 12288 + 65536 + 32768) {
    int j = i - 77824;
    wW2[j] = f2bf(W2[j]);
  }
}

__global__ void k0b_wu(const float* __restrict__ Wq, const float* __restrict__ Wk,
                       float* __restrict__ Wu)
{
  int a = blockIdx.x, b = threadIdx.x;
  float acc = 0.f;
  #pragma unroll 4
  for (int h = 0; h < 256; ++h)
    acc += Wq[h*256 + a] * Wk[h*256 + b];
  Wu[a*256 + b] = acc;
}

__global__ void k0c_G(const float* __restrict__ Wu,
                      const float* __restrict__ Wk1, const float* __restrict__ bk1,
                      const float* __restrict__ Wk2, const float* __restrict__ bk2,
                      float* __restrict__ G, float* __restrict__ g)
{
  int j = blockIdx.x, a = threadIdx.x;
  const float* Wkj = j ? Wk2 : Wk1;
  const float* bkj = j ? bk2 : bk1;
  float acc[13];
  #pragma unroll
  for (int q = 0; q < 13; ++q) acc[q] = 0.f;
  float ga = 0.f;
  for (int b = 0; b < 256; ++b) {
    float wu = Wu[a*256 + b];
    #pragma unroll
    for (int q = 0; q < 13; ++q) acc[q] += wu * Wkj[b*13 + q];
    ga += wu * bkj[b];
  }
  #pragma unroll
  for (int q = 0; q < 13; ++q) G[j*3328 + a*13 + q] = acc[q];
  g[j*256 + a] = ga;
}

__global__ void k0d_M(const float* __restrict__ We, const float* __restrict__ be,
                      const float* __restrict__ G, const float* __restrict__ g,
                      float* __restrict__ scp)
{
  int j = blockIdx.x, t = threadIdx.x;
  float acc = 0.f;
  if (t < 169) {
    int p = t / 13, q = t - p*13;
    for (int a = 0; a < 256; ++a) acc += We[a*13 + p] * G[j*3328 + a*13 + q];
    scp[j*256 + t] = acc;
  } else if (t < 182) {
    int p = t - 169;
    for (int a = 0; a < 256; ++a) acc += We[a*13 + p] * g[j*256 + a];
    scp[j*256 + t] = acc;
  } else if (t < 195) {
    int q = t - 182;
    for (int a = 0; a < 256; ++a) acc += be[a] * G[j*3328 + a*13 + q];
    scp[j*256 + t] = acc;
  } else if (t == 195) {
    for (int a = 0; a < 256; ++a) acc += be[a] * g[j*256 + a];
    scp[j*256 + 195] = acc;
  }
}

__global__ __launch_bounds__(256) void k0e_scores(const float* __restrict__ x,
                                                  const float* __restrict__ scp,
                                                  float* __restrict__ wrow)
{
  int row = blockIdx.x * 256 + threadIdx.x;
  const float* xr = x + (size_t)row*39;
  float f0[13], f1[13], f2[13];
  #pragma unroll
  for (int p = 0; p < 12; ++p) { f0[p] = xr[p]; f1[p] = xr[12+p]; f2[p] = xr[24+p]; }
  f0[12] = xr[36]; f1[12] = xr[37]; f2[12] = xr[38];

  auto score = [&](const float* __restrict__ P, const float (&fj)[13]) -> float {
    float s = P[195];
    #pragma unroll
    for (int p = 0; p < 13; ++p) {
      float tp = P[169 + p];
      #pragma unroll
      for (int q = 0; q < 13; ++q) tp += P[p*13 + q] * fj[q];
      s += f0[p] * tp;
    }
    #pragma unroll
    for (int q = 0; q < 13; ++q) s += P[182 + q] * fj[q];
    return s;
  };
  float s1 = score(scp, f1);
  float s2 = score(scp + 256, f2);
  wrow[row] = 1.f / (1.f + __expf((s2 - s1) * 0.0625f));   // /sqrt(256)
}

// ---------------- staging (512 threads) ----------------
__device__ __forceinline__ void ldw_issue(const u16* __restrict__ src, int stride,
                                          int t, s16x8* ld)
{
  #pragma unroll
  for (int i = 0; i < 2; ++i) {
    int u = t + i*512;
    ld[i] = *(const s16x8*)(src + (u >> 4)*stride + (u & 15)*8);
  }
}
__device__ __forceinline__ void ldw_write(u8* __restrict__ smem_, int p, int t, const s16x8* ld)
{
  #pragma unroll
  for (int i = 0; i < 2; ++i) {
    int u = t + i*512;
    *(s16x8*)(smem_ + WBo(p) + WIDX(u >> 4, (u & 15)*16)) = ld[i];
  }
}

// bfr for embed: K=16: koct0 -> obs[12a+0..7]; koct1 -> obs[12a+8..11], action, 0,0,0
__device__ __forceinline__ s16x8 make_bfr32(const float* __restrict__ xr, int a, int koct)
{
  s16x8 v = {0,0,0,0,0,0,0,0};
  if (koct == 0) {
    #pragma unroll
    for (int e = 0; e < 8; ++e) v[e] = (short)f2bf(xr[12*a + e]);
  } else {
    #pragma unroll
    for (int e = 0; e < 4; ++e) v[e] = (short)f2bf(xr[12*a + 8 + e]);
    v[4] = (short)f2bf(xr[36 + a]);
  }
  return v;
}

// embed: wave (nt, mg) computes feats mg*128..+127 (4 mt32) for cols nt*32..+31; K=16
__device__ __forceinline__ void embed_c32(const u8* __restrict__ wb, u8* __restrict__ act,
    const float* __restrict__ bias, s16x8 bfr, int nt, int mg, int l31, int koct)
{
  #pragma unroll
  for (int jj = 0; jj < 4; ++jj) {
    const int mt = mg*4 + jj;
    s16x8 a = *(const s16x8*)(wb + EIDX2(mt*32 + l31, koct*16));
    f32x16 acc = zero16();
    acc = MFMA32(a, bfr, acc, 0, 0, 0);
    #pragma unroll
    for (int g = 0; g < 4; ++g) {
      f32x4 bb = ((const f32x4*)bias)[mt*8 + 2*g + koct];
      s16x4 pk;
      #pragma unroll
      for (int r = 0; r < 4; ++r) pk[r] = (short)f2bf(acc[4*g + r] + bb[r]);
      *(s16x4*)(act + AIDX(nt*32 + l31, (mt*32 + 8*g + 4*koct)*2)) = pk;
    }
  }
}

// ---- merged pipelined attention: e_q -> ACT_EQ, atten -> ACT_WK; returns WB parity.
// chunks: c0..c2 = embA0..2, c3..c10 = V(kh=m>>2, o=m&3), tails c11..c13 (optional).
// V staged ONCE; each chunk multiplied by BOTH e_k1 and e_k2 B-sets. 2-deep prefetch.
__device__ __forceinline__ int attn_run32(
    u8* __restrict__ smem, const float* __restrict__ x, int rowbase,
    const u16* __restrict__ wEmb16, const float* __restrict__ be,
    const float* __restrict__ bk1, const float* __restrict__ bk2,
    const u16* __restrict__ wV, const float* __restrict__ bv,
    const float* __restrict__ wrow,
    const u16* __restrict__ n11, int s11, const u16* __restrict__ n12, int s12,
    const u16* __restrict__ n13, int s13,
    int t, s16x8* ldA, s16x8* ldB)
{
  const int lane = t & 63;
  const int l31 = lane & 31, koct = lane >> 5;
  const int wv_ = t >> 6;
  const int nt = wv_ & 3, mg = wv_ >> 2;
  const int myrow = rowbase + nt*32 + l31;
  const float w1 = wrow[myrow];
  const float* xr = x + (size_t)myrow*39;
  s16x8 bfr0 = make_bfr32(xr, 0, koct);
  s16x8 bfr1 = make_bfr32(xr, 1, koct);
  s16x8 bfr2 = make_bfr32(xr, 2, koct);

  // prologue: c0,c1 issued; c0 written; c2 issued
  ldA[0] = *(const s16x8*)(wEmb16 + t*8);           // c0
  ldB[0] = *(const s16x8*)(wEmb16 + 4096 + t*8);    // c1
  *(s16x8*)(smem + WBo(0) + EIDX2(t >> 1, (t & 1)*16)) = ldA[0];
  ldA[0] = *(const s16x8*)(wEmb16 + 8192 + t*8);    // c2
  BARX();
  int p = 0;

  // phase0: compute c0 (emb0 -> EQ); write c1 (B); issue c3 -> B
  *(s16x8*)(smem + WBo(p^1) + EIDX2(t >> 1, (t & 1)*16)) = ldB[0];
  ldw_issue(wV, 256, t, ldB);                       // c3 = V(kh0,o0)
  embed_c32(smem + WBo(p), smem + ACT_EQ, be, bfr0, nt, mg, l31, koct);
  BARX(); p ^= 1;

  // phase1: compute c1 (emb1 -> WK = e_k1); write c2 (A); issue c4 -> A
  *(s16x8*)(smem + WBo(p^1) + EIDX2(t >> 1, (t & 1)*16)) = ldA[0];
  ldw_issue(wV + 16384, 256, t, ldA);               // c4 = V(kh0,o1)
  embed_c32(smem + WBo(p), smem + ACT_WK, bk1, bfr1, nt, mg, l31, koct);
  BARX(); p ^= 1;

  // phase2: hoist ALL e_k1 B-frags; guard barrier; compute c2 (emb2 -> WK = e_k2);
  //         write c3 (B); issue c5 -> B
  s16x8 bqv1[16];
  #pragma unroll
  for (int kh = 0; kh < 2; ++kh)
    #pragma unroll
    for (int ks = 0; ks < 8; ++ks)
      bqv1[kh*8+ks] = *(const s16x8*)(smem + ACT_WK +
          AIDX(nt*32 + l31, kh*256 + ks*32 + koct*16));
  BARX();                                           // all e_k1 reads done before overwrite
  ldw_write(smem, p^1, t, ldB);                     // c3
  ldw_issue(wV + 2*16384, 256, t, ldB);             // c5 = V(kh0,o2)
  embed_c32(smem + WBo(p), smem + ACT_WK, bk2, bfr2, nt, mg, l31, koct);
  BARX(); p ^= 1;

  f32x16 accV1[4], accV2[4];
  #pragma unroll
  for (int o = 0; o < 4; ++o) { accV1[o] = zero16(); accV2[o] = zero16(); }
  s16x8 bqv2[16];

  // V loop: 8 chunks c3..c10 = V(kh=j>>2, o=j&3); each chunk x {e_k1, e_k2}
  #pragma unroll
  for (int j = 0; j < 8; ++j) {
    const int kh = j >> 2, o = j & 3;
    if (j == 0) {
      #pragma unroll
      for (int kh2 = 0; kh2 < 2; ++kh2)
        #pragma unroll
        for (int ks = 0; ks < 8; ++ks)
          bqv2[kh2*8+ks] = *(const s16x8*)(smem + ACT_WK +
              AIDX(nt*32 + l31, kh2*256 + ks*32 + koct*16));
    }
    // write c4+j (set: j even -> A); issue c6+j into same set
    s16x8* wset = (j & 1) ? ldB : ldA;
    if (j < 7)       ldw_write(smem, p^1, t, wset);
    else if (n11)    ldw_write(smem, p^1, t, wset);  // c11
    if (j < 5)       { const int m = j + 3; ldw_issue(wV + (m&3)*16384 + (m>>2)*128, 256, t, wset); }
    else if (j == 5) { if (n11) ldw_issue(n11, s11, t, wset); }
    else if (j == 6) { if (n12) ldw_issue(n12, s12, t, wset); }
    else             { if (n13) ldw_issue(n13, s13, t, wset); }
    #pragma unroll
    for (int ks = 0; ks < 8; ++ks) {
      s16x8 a = *(const s16x8*)(smem + WBo(p) + WIDX(mg*32 + l31, ks*32 + koct*16));
      accV1[o] = MFMA32(a, bqv1[kh*8+ks], accV1[o], 0, 0, 0);
      accV2[o] = MFMA32(a, bqv2[kh*8+ks], accV2[o], 0, 0, 0);
    }
    if (j == 7) {
      const float w2 = 1.f - w1;
      #pragma unroll
      for (int o2 = 0; o2 < 4; ++o2)
        #pragma unroll
        for (int g = 0; g < 4; ++g) {
          f32x4 bb = ((const f32x4*)bv)[o2*16 + mg*8 + 2*g + koct];
          s16x4 pk;
          #pragma unroll
          for (int r = 0; r < 4; ++r) {
            float va = accV1[o2][4*g + r] + bb[r]; va = (va > 0.f) ? va : 0.01f*va;
            float vb = accV2[o2][4*g + r] + bb[r]; vb = (vb > 0.f) ? vb : 0.01f*vb;
            pk[r] = (short)f2bf(w1*va + w2*vb);
          }
          *(s16x4*)(smem + ACT_WK + AIDX(nt*32 + l31, (o2*64 + mg*32 + 8*g + 4*koct)*2)) = pk;
        }
    }
    BARX(); p ^= 1;
  }
  return p;   // WB[p]=c11, c12 in ldA, c13 in ldB (when tails present)
}

// ---------------- K1: attention -> BN partial sums (+ X-atten store) ----------------
template<bool WRITEX>
__global__ __launch_bounds__(512) __attribute__((amdgpu_waves_per_eu(1, 2)))
void k1_attn(
    const float* __restrict__ x,
    const u16* __restrict__ wEmb16, const float* __restrict__ be,
    const float* __restrict__ bk1, const float* __restrict__ bk2,
    const u16* __restrict__ wV, const float* __restrict__ bv,
    const float* __restrict__ wrow,
    float* __restrict__ pA, float* __restrict__ pB,
    u8* __restrict__ xatt)
{
  __shared__ __align__(16) u8 smem[SMEM_BYTES];
  const int t = threadIdx.x;
  const int wt = blockIdx.x;
  const int rowbase = wt * 128;
  s16x8 ldA[2], ldB[2];

  attn_run32(smem, x, rowbase, wEmb16, be, bk1, bk2, wV, bv, wrow,
             nullptr, 0, nullptr, 0, nullptr, 0, t, ldA, ldB);

  if (WRITEX) {
    u8* dst = xatt + (size_t)wt*65536;
    #pragma unroll
    for (int j = 0; j < 8; ++j)
      *(u32x4*)(dst + j*8192 + t*16) = *(const u32x4*)(smem + ACT_WK + j*8192 + t*16);
  }

  // stats: thread t = (fg = t&63 feat-octet, cb = t>>6 col-block of 16)
  const int fg = t & 63, cb = t >> 6;
  const u8* rg = smem + ((fg & 32) ? ACT_WK : ACT_EQ);
  const int fb = (fg & 31) * 16;
  float s[8], q[8];
  #pragma unroll
  for (int e = 0; e < 8; ++e) { s[e] = 0.f; q[e] = 0.f; }
  #pragma unroll 4
  for (int c = 0; c < 16; ++c) {
    int col = cb*16 + c;
    u32x4 v = *(const u32x4*)(rg + AIDX(col, fb));
    #pragma unroll
    for (int j = 0; j < 4; ++j) {
      float a = bf2f((u16)(v[j] & 0xFFFFu));
      float b = bf2f((u16)(v[j] >> 16));
      s[2*j] += a; q[2*j] += a*a;
      s[2*j+1] += b; q[2*j+1] += b*b;
    }
  }
  float* sb = (float*)(smem + WB0_OFF);
  #pragma unroll
  for (int e = 0; e < 8; ++e) {
    sb[(fg*8 + e)*8 + cb]        = s[e];
    sb[4096 + (fg*8 + e)*8 + cb] = q[e];
  }
  __syncthreads();
  {
    int f = t;
    float ss = 0.f, qs = 0.f;
    #pragma unroll
    for (int c2 = 0; c2 < 8; ++c2) { ss += sb[f*8 + c2]; qs += sb[4096 + f*8 + c2]; }
    pA[(size_t)wt*512 + f] = ss;
    pB[(size_t)wt*512 + f] = qs;
  }
}

// ---------------- KR1 / KR2 / K2b ----------------
__global__ void kR1_reduce(const float* __restrict__ pA, const float* __restrict__ pB,
                           float* __restrict__ qA, float* __restrict__ qB)
{
  int g = blockIdx.x, t = threadIdx.x;   // 256 x 256
  float2 sA = make_float2(0.f, 0.f), sB = make_float2(0.f, 0.f);
  #pragma unroll
  for (int k = 0; k < 8; ++k) {
    size_t wg = (size_t)g*8 + k;
    float2 a = *(const float2*)(pA + wg*512 + 2*t);
    float2 b = *(const float2*)(pB + wg*512 + 2*t);
    sA.x += a.x; sA.y += a.y; sB.x += b.x; sB.y += b.y;
  }
  *(float2*)(qA + (size_t)g*512 + 2*t) = sA;
  *(float2*)(qB + (size_t)g*512 + 2*t) = sB;
}

__global__ void kR2_stats(const float* __restrict__ qA, const float* __restrict__ qB,
                          float* __restrict__ mu, float* __restrict__ rstd)
{
  int f = blockIdx.x, t = threadIdx.x;   // 512 x 256
  float s = qA[(size_t)t*512 + f];
  float q = qB[(size_t)t*512 + f];
  #pragma unroll
  for (int off = 1; off < 64; off <<= 1) {
    s += __shfl_xor(s, off);
    q += __shfl_xor(q, off);
  }
  __shared__ float ls[4], lq[4];
  if ((t & 63) == 0) { ls[t >> 6] = s; lq[t >> 6] = q; }
  __syncthreads();
  if (t == 0) {
    float S = ls[0]+ls[1]+ls[2]+ls[3];
    float Q = lq[0]+lq[1]+lq[2]+lq[3];
    float m = S * (1.f/262144.f);
    float v = Q * (1.f/262144.f) - m*m;
    mu[f] = m;
    rstd[f] = 1.f / sqrtf(v + 1e-5f);
  }
}

__global__ void k2b_fold(const float* __restrict__ W1, const float* __restrict__ b1,
                         const float* __restrict__ mu, const float* __restrict__ rstd,
                         u16* __restrict__ W1s, float* __restrict__ b1eff)
{
  int o = blockIdx.x, t = threadIdx.x;
  float local = 0.f;
  #pragma unroll
  for (int k = 0; k < 2; ++k) {
    int f = t + k*256;
    float w = W1[o*512 + f];
    float r = rstd[f];
    W1s[o*512 + f] = f2bf(w * r);
    local += w * r * mu[f];
  }
  #pragma unroll
  for (int off = 1; off < 64; off <<= 1) local += __shfl_xor(local, off);
  __shared__ float ls[4];
  if ((t & 63) == 0) ls[t >> 6] = local;
  __syncthreads();
  if (t == 0) b1eff[o] = b1[o] - (ls[0]+ls[1]+ls[2]+ls[3]);
}

// ---------------- K3: MLP (attention from X-cache or recompute) ----------------
template<bool USEX>
__global__ __launch_bounds__(512) __attribute__((amdgpu_waves_per_eu(1, 2)))
void k3_mlp(
    const float* __restrict__ x,
    const u16* __restrict__ wEmb16, const float* __restrict__ be,
    const float* __restrict__ bk1, const float* __restrict__ bk2,
    const u16* __restrict__ wV, const float* __restrict__ bv,
    const float* __restrict__ wrow,
    const u16* __restrict__ W1s, const float* __restrict__ b1eff,
    const u16* __restrict__ wW2, const float* __restrict__ b2,
    const float* __restrict__ W3, const float* __restrict__ b3,
    const u8* __restrict__ xatt,
    float* __restrict__ out)
{
  __shared__ __align__(16) u8 smem[SMEM_BYTES];
  const int t = threadIdx.x;
  const int wt = blockIdx.x;
  const int rowbase = wt * 128;
  const int lane = t & 63;
  const int l31 = lane & 31, koct = lane >> 5;
  const int wv_ = t >> 6;
  const int ng = wv_ & 3, mgw = wv_ >> 2;
  s16x8 ldA[2], ldB[2];
  int p;

  if constexpr (USEX) {
    // prologue (oldest-first): embA0, X tile, g0 -> B, g1 -> A
    s16x8 e0 = *(const s16x8*)(wEmb16 + t*8);
    s16x8 xl[8];
    const u8* xs = xatt + (size_t)wt*65536;
    #pragma unroll
    for (int j = 0; j < 8; ++j) xl[j] = *(const s16x8*)(xs + j*8192 + t*16);
    ldw_issue(W1s, 512, t, ldB);            // g0
    ldw_issue(W1s + 32768, 512, t, ldA);    // g1
    *(s16x8*)(smem + WBo(0) + EIDX2(t >> 1, (t & 1)*16)) = e0;
    BARX();
    p = 0;
    // P0: compute embA0 -> EQ; write g0 (B); issue g2 -> B; write X -> WK
    ldw_write(smem, p^1, t, ldB);           // g0
    ldw_issue(W1s + 65536, 512, t, ldB);    // g2
    {
      const float* xr = x + (size_t)(rowbase + ng*32 + l31)*39;
      embed_c32(smem + WBo(p), smem + ACT_EQ, be, make_bfr32(xr, 0, koct), ng, mgw, l31, koct);
    }
    #pragma unroll
    for (int j = 0; j < 8; ++j)
      *(s16x8*)(smem + ACT_WK + j*8192 + t*16) = xl[j];
    BARX(); p ^= 1;
  } else {
    // tails: g0 = W1s chunk0, g1 = chunk1, g2 = chunk2
    p = attn_run32(smem, x, rowbase, wEmb16, be, bk1, bk2, wV, bv, wrow,
                   W1s, 512, W1s + 32768, 512, W1s + 65536, 512, t, ldA, ldB);
  }
  // invariant: WB[p] = g0, g1 in ldA, g2 in ldB

  // GEMM1: g0..g15 = W1s(o=c&3, q=c>>2); B: q0,q1 = e_q (EQ), q2,q3 = atten (WK)
  f32x16 acc1[4];
  #pragma unroll
  for (int o = 0; o < 4; ++o) acc1[o] = zero16();
  s16x8 bq[8];

  #pragma unroll
  for (int i = 0; i < 16; ++i) {
    if ((i & 3) == 0) {
      const int areg = (i < 8) ? ACT_EQ : ACT_WK;
      const int qb = ((i >> 2) & 1) * 256;
      #pragma unroll
      for (int ks = 0; ks < 8; ++ks)
        bq[ks] = *(const s16x8*)(smem + areg + AIDX(ng*32 + l31, qb + ks*32 + koct*16));
    }
    s16x8* wset = (i & 1) ? ldB : ldA;      // g(i+1): i even -> A
    ldw_write(smem, p^1, t, wset);
    {
      const int nx = i + 3;
      if (nx < 16)      ldw_issue(W1s + (size_t)(nx&3)*32768 + (nx>>2)*128, 512, t, wset);
      else if (nx < 20) { const int j2 = nx - 16;
                          ldw_issue(wW2 + (size_t)(j2&1)*16384 + (j2>>1)*128, 256, t, wset); }
    }
    #pragma unroll
    for (int ks = 0; ks < 8; ++ks) {
      s16x8 a = *(const s16x8*)(smem + WBo(p) + WIDX(mgw*32 + l31, ks*32 + koct*16));
      acc1[i & 3] = MFMA32(a, bq[ks], acc1[i & 3], 0, 0, 0);
    }
    if (i == 15) {
      // h1 = relu(acc1 + b1eff) -> ACT_EQ
      #pragma unroll
      for (int o2 = 0; o2 < 4; ++o2)
        #pragma unroll
        for (int g = 0; g < 4; ++g) {
          f32x4 bb = ((const f32x4*)b1eff)[o2*16 + mgw*8 + 2*g + koct];
          s16x4 pk;
          #pragma unroll
          for (int r = 0; r < 4; ++r) {
            float v = acc1[o2][4*g + r] + bb[r];
            pk[r] = (short)f2bf((v > 0.f) ? v : 0.f);
          }
          *(s16x4*)(smem + ACT_EQ + AIDX(ng*32 + l31, (o2*64 + mgw*32 + 8*g + 4*koct)*2)) = pk;
        }
    }
    BARX(); p ^= 1;
  }

  // GEMM2: g16..g19 = W2(o=(c-16)&1, q=(c-16)>>1); B = h1 (EQ)
  f32x16 acc2[2];
  #pragma unroll
  for (int o = 0; o < 2; ++o) acc2[o] = zero16();

  #pragma unroll
  for (int i = 16; i < 20; ++i) {
    if (((i - 16) & 1) == 0) {
      const int qb = ((i - 16) >> 1) * 256;
      #pragma unroll
      for (int ks = 0; ks < 8; ++ks)
        bq[ks] = *(const s16x8*)(smem + ACT_EQ + AIDX(ng*32 + l31, qb + ks*32 + koct*16));
    }
    s16x8* wset = (i & 1) ? ldB : ldA;
    if (i < 19) ldw_write(smem, p^1, t, wset);
    {
      const int nx = i + 3;
      if (nx < 20) { const int j2 = nx - 16;
                     ldw_issue(wW2 + (size_t)(j2&1)*16384 + (j2>>1)*128, 256, t, wset); }
    }
    #pragma unroll
    for (int ks = 0; ks < 8; ++ks) {
      s16x8 a = *(const s16x8*)(smem + WBo(p) + WIDX(mgw*32 + l31, ks*32 + koct*16));
      acc2[(i - 16) & 1] = MFMA32(a, bq[ks], acc2[(i - 16) & 1], 0, 0, 0);
    }
    if (i == 19) {
      // h2 = relu(acc2 + b2) -> ACT_WK
      #pragma unroll
      for (int o2 = 0; o2 < 2; ++o2)
        #pragma unroll
        for (int g = 0; g < 4; ++g) {
          f32x4 bb = ((const f32x4*)b2)[o2*16 + mgw*8 + 2*g + koct];
          s16x4 pk;
          #pragma unroll
          for (int r = 0; r < 4; ++r) {
            float v = acc2[o2][4*g + r] + bb[r];
            pk[r] = (short)f2bf((v > 0.f) ? v : 0.f);
          }
          *(s16x4*)(smem + ACT_WK + AIDX(ng*32 + l31, (o2*64 + mgw*32 + 8*g + 4*koct)*2)) = pk;
        }
    }
    BARX(); p ^= 1;
  }

  // out = W3 . h2 + b3 (one thread per row)
  if (t < 128) {
    float s = b3[0];
    #pragma unroll
    for (int jj = 0; jj < 16; ++jj) {
      const u32x4 v = *(const u32x4*)(smem + ACT_WK + AIDX(t, jj*16));
      #pragma unroll
      for (int q2 = 0; q2 < 4; ++q2) {
        u32 u = v[q2];
        s += bf2f((u16)(u & 0xFFFFu)) * W3[jj*8 + q2*2];
        s += bf2f((u16)(u >> 16))     * W3[jj*8 + q2*2 + 1];
      }
    }
    out[rowbase + t] = s;
  }
}

extern "C" void kernel_launch(void* const* d_in, const int* in_sizes, int n_in,
                              void* d_out, int out_size, void* d_ws, size_t ws_size,
                              hipStream_t stream)
{
  const float* x   = (const float*)d_in[0];
  const float* We  = (const float*)d_in[1];
  const float* be  = (const float*)d_in[2];
  const float* Wk1 = (const float*)d_in[3];
  const float* bk1 = (const float*)d_in[4];
  const float* Wk2 = (const float*)d_in[5];
  const float* bk2 = (const float*)d_in[6];
  const float* Wq  = (const float*)d_in[7];
  const float* Wk  = (const float*)d_in[8];
  const float* Wv  = (const float*)d_in[9];
  const float* bv  = (const float*)d_in[10];
  const float* W1  = (const float*)d_in[11];
  const float* b1  = (const float*)d_in[12];
  const float* W2  = (const float*)d_in[13];
  const float* b2  = (const float*)d_in[14];
  const float* W3  = (const float*)d_in[15];
  const float* b3  = (const float*)d_in[16];

  u8* ws = (u8*)d_ws;
  float* pA    = (float*)(ws + PA_OFF);
  float* pB    = (float*)(ws + PB_OFF);
  float* qA    = (float*)(ws + QA_OFF);
  float* qB    = (float*)(ws + QB_OFF);
  float* mu    = (float*)(ws + MU_OFF);
  float* rstd  = (float*)(ws + RSTD_OFF);
  float* b1eff = (float*)(ws + B1E_OFF);
  u16*   wEmb  = (u16*)(ws + WEMB_OFF);
  u16*   wVb   = (u16*)(ws + WV_OFF);
  u16*   wW2   = (u16*)(ws + W2_OFF);
  u16*   wW1s  = (u16*)(ws + W1S_OFF);
  float* Wu    = (float*)(ws + WU_OFF);
  float* G     = (float*)(ws + G_OFF);
  float* g     = (float*)(ws + GG_OFF);
  float* scp   = (float*)(ws + SCP_OFF);
  float* wrow  = (float*)(ws + WROW_OFF);
  u8*    xatt  = ws + XA_OFF;

  const bool useX = (ws_size >= WS_NEED_X);

  k0_convert<<<dim3(432), dim3(256), 0, stream>>>(We, Wk1, Wk2, Wv, W2, wEmb, wVb, wW2);
  k0b_wu<<<dim3(256), dim3(256), 0, stream>>>(Wq, Wk, Wu);
  k0c_G<<<dim3(2), dim3(256), 0, stream>>>(Wu, Wk1, bk1, Wk2, bk2, G, g);
  k0d_M<<<dim3(2), dim3(256), 0, stream>>>(We, be, G, g, scp);
  k0e_scores<<<dim3(1024), dim3(256), 0, stream>>>(x, scp, wrow);
  if (useX) {
    k1_attn<true><<<dim3(NTILE), dim3(512), 0, stream>>>(x, wEmb, be, bk1, bk2, wVb, bv,
                                                         wrow, pA, pB, xatt);
  } else {
    k1_attn<false><<<dim3(NTILE), dim3(512), 0, stream>>>(x, wEmb, be, bk1, bk2, wVb, bv,
                                                          wrow, pA, pB, xatt);
  }
  kR1_reduce<<<dim3(256), dim3(256), 0, stream>>>(pA, pB, qA, qB);
  kR2_stats<<<dim3(512), dim3(256), 0, stream>>>(qA, qB, mu, rstd);
  k2b_fold<<<dim3(256), dim3(256), 0, stream>>>(W1, b1, mu, rstd, wW1s, b1eff);
  if (useX) {
    k3_mlp<true><<<dim3(NTILE), dim3(512), 0, stream>>>(x, wEmb, be, bk1, bk2, wVb, bv, wrow,
                                                        wW1s, b1eff, wW2, b2, W3, b3, xatt,
                                                        (float*)d_out);
  } else {
    k3_mlp<false><<<dim3(NTILE), dim3(512), 0, stream>>>(x, wEmb, be, bk1, bk2, wVb, bv, wrow,
                                                         wW1s, b1eff, wW2, b2, W3, b3, xatt,
                                                         (float*)d_out);
  }
}

// Round 13
// 385.591 us; speedup vs baseline: 1.0933x; 1.0933x over previous
//
#include <hip/hip_runtime.h>
#include <cstdint>
#include <cstddef>

typedef unsigned char  u8;
typedef unsigned short u16;
typedef unsigned int   u32;

typedef __attribute__((ext_vector_type(8)))  short s16x8;
typedef __attribute__((ext_vector_type(4)))  short s16x4;
typedef __attribute__((ext_vector_type(4)))  float f32x4;
typedef __attribute__((ext_vector_type(16))) float f32x16;
typedef __attribute__((ext_vector_type(4)))  u32   u32x4;

#define NTILE 2048   // 262144 / 128 rows per tile

// LDS: ACT_EQ 64KB + ACT_WK 64KB + WB 2x16KB = 160KB
#define ACT_EQ 0
#define ACT_WK 65536
#define WB0_OFF 131072
#define WBSZ    16384
#define SMEM_BYTES 163840
#define WBo(p) (WB0_OFF + (p)*WBSZ)

// XOR-swizzled layouts
#define AIDX(col, fb)  ((((col)*512) + (fb)) ^ (((col)&7) << 4))      // act [128 col][512B]
#define WIDX(row, kb)  ((((row)*256) + (kb)) ^ (((row)&15) << 4))     // wchunk [64 row][256B], 16-slot
#define EIDX2(row, kb) ((((row)*32)  + (kb)) ^ ((((row)>>2)&1) << 4)) // emb16 [256 row][32B]

#define MFMA32 __builtin_amdgcn_mfma_f32_32x32x16_bf16

// raw barrier: LDS visibility without draining vmem (prefetch survives)
#define BARX() do { __builtin_amdgcn_sched_barrier(0); \
  asm volatile("s_waitcnt lgkmcnt(0)"); \
  __builtin_amdgcn_s_barrier(); \
  __builtin_amdgcn_sched_barrier(0); } while (0)

// ---------------- workspace layout (bytes) ----------------
static const size_t PA_OFF   = 0;          // f32 [2048 tile][512 f]
static const size_t PB_OFF   = 4194304;
static const size_t QA_OFF   = 8388608;    // f32 [256 g][512 f]
static const size_t QB_OFF   = 8912896;
static const size_t MU_OFF   = 9437184;
static const size_t RSTD_OFF = 9439232;
static const size_t B1E_OFF  = 9441280;
static const size_t WEMB_OFF = 9442304;    // bf16 [3][256][16]
static const size_t WV_OFF   = 9491456;    // bf16 [256][256]
static const size_t W2_OFF   = 9622528;    // bf16 [128][256]
static const size_t W1S_OFF  = 9688064;    // bf16 [256][512]
static const size_t WU_OFF   = 9950208;    // f32 [256][256]
static const size_t G_OFF    = 10212352;   // f32 [2][256][13]
static const size_t GG_OFF   = 10238976;   // f32 [2][256]
static const size_t SCP_OFF  = 10241024;   // f32 [2][256]
static const size_t WROW_OFF = 10243072;   // f32 [262144]
static const size_t XA_OFF   = 11534336;   // pre-swizzled atten tiles [2048][65536B]
static const size_t WS_NEED_X = XA_OFF + (size_t)2048*65536;   // 145,752,064

__device__ __forceinline__ u16 f2bf(float f) {
  u32 u = __builtin_bit_cast(u32, f);
  u += 0x7FFFu + ((u >> 16) & 1u);     // RNE
  return (u16)(u >> 16);
}
__device__ __forceinline__ float bf2f(u16 h) {
  u32 u = ((u32)h) << 16;
  return __builtin_bit_cast(float, u);
}
__device__ __forceinline__ f32x16 zero16() {
  f32x16 z;
  #pragma unroll
  for (int i = 0; i < 16; ++i) z[i] = 0.f;
  return z;
}

// ---------------- K0 setup kernels ----------------
__global__ void k0_convert(const float* __restrict__ We,  const float* __restrict__ Wk1,
                           const float* __restrict__ Wk2, const float* __restrict__ Wv,
                           const float* __restrict__ W2,
                           u16* __restrict__ wEmb, u16* __restrict__ wV, u16* __restrict__ wW2)
{
  int i = blockIdx.x * 256 + threadIdx.x;
  if (i < 12288) {                          // emb16 [agent][256][16]
    int which = i >> 12, rem = i & 4095, h = rem >> 4, c = rem & 15;
    const float* W = (which == 0) ? We : (which == 1) ? Wk1 : Wk2;
    wEmb[i] = (c < 13) ? f2bf(W[h*13 + c]) : (u16)0;
  } else if (i < 12288 + 65536) {
    int j = i - 12288;
    wV[j] = f2bf(Wv[j]);
  } else if (i < 12288 + 65536 + 32768) {
    int j = i - 77824;
    wW2[j] = f2bf(W2[j]);
  }
}

__global__ void k0b_wu(const float* __restrict__ Wq, const float* __restrict__ Wk,
                       float* __restrict__ Wu)
{
  int a = blockIdx.x, b = threadIdx.x;
  float acc = 0.f;
  #pragma unroll 4
  for (int h = 0; h < 256; ++h)
    acc += Wq[h*256 + a] * Wk[h*256 + b];
  Wu[a*256 + b] = acc;
}

__global__ void k0c_G(const float* __restrict__ Wu,
                      const float* __restrict__ Wk1, const float* __restrict__ bk1,
                      const float* __restrict__ Wk2, const float* __restrict__ bk2,
                      float* __restrict__ G, float* __restrict__ g)
{
  int j = blockIdx.x, a = threadIdx.x;
  const float* Wkj = j ? Wk2 : Wk1;
  const float* bkj = j ? bk2 : bk1;
  float acc[13];
  #pragma unroll
  for (int q = 0; q < 13; ++q) acc[q] = 0.f;
  float ga = 0.f;
  for (int b = 0; b < 256; ++b) {
    float wu = Wu[a*256 + b];
    #pragma unroll
    for (int q = 0; q < 13; ++q) acc[q] += wu * Wkj[b*13 + q];
    ga += wu * bkj[b];
  }
  #pragma unroll
  for (int q = 0; q < 13; ++q) G[j*3328 + a*13 + q] = acc[q];
  g[j*256 + a] = ga;
}

__global__ void k0d_M(const float* __restrict__ We, const float* __restrict__ be,
                      const float* __restrict__ G, const float* __restrict__ g,
                      float* __restrict__ scp)
{
  int j = blockIdx.x, t = threadIdx.x;
  float acc = 0.f;
  if (t < 169) {
    int p = t / 13, q = t - p*13;
    for (int a = 0; a < 256; ++a) acc += We[a*13 + p] * G[j*3328 + a*13 + q];
    scp[j*256 + t] = acc;
  } else if (t < 182) {
    int p = t - 169;
    for (int a = 0; a < 256; ++a) acc += We[a*13 + p] * g[j*256 + a];
    scp[j*256 + t] = acc;
  } else if (t < 195) {
    int q = t - 182;
    for (int a = 0; a < 256; ++a) acc += be[a] * G[j*3328 + a*13 + q];
    scp[j*256 + t] = acc;
  } else if (t == 195) {
    for (int a = 0; a < 256; ++a) acc += be[a] * g[j*256 + a];
    scp[j*256 + 195] = acc;
  }
}

__global__ __launch_bounds__(256) void k0e_scores(const float* __restrict__ x,
                                                  const float* __restrict__ scp,
                                                  float* __restrict__ wrow)
{
  int row = blockIdx.x * 256 + threadIdx.x;
  const float* xr = x + (size_t)row*39;
  float f0[13], f1[13], f2[13];
  #pragma unroll
  for (int p = 0; p < 12; ++p) { f0[p] = xr[p]; f1[p] = xr[12+p]; f2[p] = xr[24+p]; }
  f0[12] = xr[36]; f1[12] = xr[37]; f2[12] = xr[38];

  auto score = [&](const float* __restrict__ P, const float (&fj)[13]) -> float {
    float s = P[195];
    #pragma unroll
    for (int p = 0; p < 13; ++p) {
      float tp = P[169 + p];
      #pragma unroll
      for (int q = 0; q < 13; ++q) tp += P[p*13 + q] * fj[q];
      s += f0[p] * tp;
    }
    #pragma unroll
    for (int q = 0; q < 13; ++q) s += P[182 + q] * fj[q];
    return s;
  };
  float s1 = score(scp, f1);
  float s2 = score(scp + 256, f2);
  wrow[row] = 1.f / (1.f + __expf((s2 - s1) * 0.0625f));   // /sqrt(256)
}

// ---------------- staging (512 threads) ----------------
__device__ __forceinline__ void ldw_issue(const u16* __restrict__ src, int stride,
                                          int t, s16x8* ld)
{
  #pragma unroll
  for (int i = 0; i < 2; ++i) {
    int u = t + i*512;
    ld[i] = *(const s16x8*)(src + (u >> 4)*stride + (u & 15)*8);
  }
}
__device__ __forceinline__ void ldw_write(u8* __restrict__ smem_, int p, int t, const s16x8* ld)
{
  #pragma unroll
  for (int i = 0; i < 2; ++i) {
    int u = t + i*512;
    *(s16x8*)(smem_ + WBo(p) + WIDX(u >> 4, (u & 15)*16)) = ld[i];
  }
}

// bfr for embed: K=16: koct0 -> obs[12a+0..7]; koct1 -> obs[12a+8..11], action, 0,0,0
__device__ __forceinline__ s16x8 make_bfr32(const float* __restrict__ xr, int a, int koct)
{
  s16x8 v = {0,0,0,0,0,0,0,0};
  if (koct == 0) {
    #pragma unroll
    for (int e = 0; e < 8; ++e) v[e] = (short)f2bf(xr[12*a + e]);
  } else {
    #pragma unroll
    for (int e = 0; e < 4; ++e) v[e] = (short)f2bf(xr[12*a + 8 + e]);
    v[4] = (short)f2bf(xr[36 + a]);
  }
  return v;
}

// embed: wave (nt, mg) computes feats mg*128..+127 (4 mt32) for cols nt*32..+31; K=16
__device__ __forceinline__ void embed_c32(const u8* __restrict__ wb, u8* __restrict__ act,
    const float* __restrict__ bias, s16x8 bfr, int nt, int mg, int l31, int koct)
{
  #pragma unroll
  for (int jj = 0; jj < 4; ++jj) {
    const int mt = mg*4 + jj;
    s16x8 a = *(const s16x8*)(wb + EIDX2(mt*32 + l31, koct*16));
    f32x16 acc = zero16();
    acc = MFMA32(a, bfr, acc, 0, 0, 0);
    #pragma unroll
    for (int g = 0; g < 4; ++g) {
      f32x4 bb = ((const f32x4*)bias)[mt*8 + 2*g + koct];
      s16x4 pk;
      #pragma unroll
      for (int r = 0; r < 4; ++r) pk[r] = (short)f2bf(acc[4*g + r] + bb[r]);
      *(s16x4*)(act + AIDX(nt*32 + l31, (mt*32 + 8*g + 4*koct)*2)) = pk;
    }
  }
}

// ---- merged pipelined attention (o-outer, low-pressure): e_q -> ACT_EQ, atten -> ACT_WK.
// chunks: c0..c2 = embA0..2, c3..c10 = V(o=j>>1, kh=j&1), tails c11..c13 (optional).
// V staged ONCE; per-o accumulators (32 regs live) + both B-sets hoisted (128 regs).
__device__ __forceinline__ int attn_run32(
    u8* __restrict__ smem, const float* __restrict__ x, int rowbase,
    const u16* __restrict__ wEmb16, const float* __restrict__ be,
    const float* __restrict__ bk1, const float* __restrict__ bk2,
    const u16* __restrict__ wV, const float* __restrict__ bv,
    const float* __restrict__ wrow,
    const u16* __restrict__ n11, int s11, const u16* __restrict__ n12, int s12,
    const u16* __restrict__ n13, int s13,
    int t, s16x8* ldA, s16x8* ldB)
{
  const int lane = t & 63;
  const int l31 = lane & 31, koct = lane >> 5;
  const int wv_ = t >> 6;
  const int nt = wv_ & 3, mg = wv_ >> 2;
  const int myrow = rowbase + nt*32 + l31;
  const float w1 = wrow[myrow];
  const float* xr = x + (size_t)myrow*39;
  s16x8 bfr0 = make_bfr32(xr, 0, koct);
  s16x8 bfr1 = make_bfr32(xr, 1, koct);
  s16x8 bfr2 = make_bfr32(xr, 2, koct);

  // prologue: c0,c1 issued; c0 written; c2 issued
  ldA[0] = *(const s16x8*)(wEmb16 + t*8);           // c0
  ldB[0] = *(const s16x8*)(wEmb16 + 4096 + t*8);    // c1
  *(s16x8*)(smem + WBo(0) + EIDX2(t >> 1, (t & 1)*16)) = ldA[0];
  ldA[0] = *(const s16x8*)(wEmb16 + 8192 + t*8);    // c2
  BARX();
  int p = 0;

  // phase0: compute c0 (emb0 -> EQ); write c1 (B); issue c3 -> B
  *(s16x8*)(smem + WBo(p^1) + EIDX2(t >> 1, (t & 1)*16)) = ldB[0];
  ldw_issue(wV, 256, t, ldB);                       // c3 = V(o0,kh0)
  embed_c32(smem + WBo(p), smem + ACT_EQ, be, bfr0, nt, mg, l31, koct);
  BARX(); p ^= 1;

  // phase1: compute c1 (emb1 -> WK = e_k1); write c2 (A); issue c4 -> A
  *(s16x8*)(smem + WBo(p^1) + EIDX2(t >> 1, (t & 1)*16)) = ldA[0];
  ldw_issue(wV + 128, 256, t, ldA);                 // c4 = V(o0,kh1)
  embed_c32(smem + WBo(p), smem + ACT_WK, bk1, bfr1, nt, mg, l31, koct);
  BARX(); p ^= 1;

  // phase2: hoist ALL e_k1 B-frags; guard barrier (cross-wave feature split);
  //         compute c2 (emb2 -> WK = e_k2); write c3 (B); issue c5 -> B
  s16x8 bqv1[16];
  #pragma unroll
  for (int kh = 0; kh < 2; ++kh)
    #pragma unroll
    for (int ks = 0; ks < 8; ++ks)
      bqv1[kh*8+ks] = *(const s16x8*)(smem + ACT_WK +
          AIDX(nt*32 + l31, kh*256 + ks*32 + koct*16));
  BARX();
  ldw_write(smem, p^1, t, ldB);                     // c3
  ldw_issue(wV + 16384, 256, t, ldB);               // c5 = V(o1,kh0)
  embed_c32(smem + WBo(p), smem + ACT_WK, bk2, bfr2, nt, mg, l31, koct);
  BARX(); p ^= 1;

  // V loop: 8 chunks c3..c10 = V(o=j>>1, kh=j&1); per-o accumulators only
  f32x16 aV1 = zero16(), aV2 = zero16();
  s16x8 bqv2[16];

  #pragma unroll
  for (int j = 0; j < 8; ++j) {
    const int o = j >> 1, kh = j & 1;
    if (j == 0) {
      #pragma unroll
      for (int kh2 = 0; kh2 < 2; ++kh2)
        #pragma unroll
        for (int ks = 0; ks < 8; ++ks)
          bqv2[kh2*8+ks] = *(const s16x8*)(smem + ACT_WK +
              AIDX(nt*32 + l31, kh2*256 + ks*32 + koct*16));
    }
    // write c4+j (set: (4+j) even -> A); issue c6+j into same set
    s16x8* wset = (j & 1) ? ldB : ldA;
    if (j < 7)       ldw_write(smem, p^1, t, wset);
    else if (n11)    ldw_write(smem, p^1, t, wset);  // c11
    if (j < 5)       { const int m = j + 3; ldw_issue(wV + (m>>1)*16384 + (m&1)*128, 256, t, wset); }
    else if (j == 5) { if (n11) ldw_issue(n11, s11, t, wset); }
    else if (j == 6) { if (n12) ldw_issue(n12, s12, t, wset); }
    else             { if (n13) ldw_issue(n13, s13, t, wset); }
    #pragma unroll
    for (int ks = 0; ks < 8; ++ks) {
      s16x8 a = *(const s16x8*)(smem + WBo(p) + WIDX(mg*32 + l31, ks*32 + koct*16));
      aV1 = MFMA32(a, bqv1[kh*8+ks], aV1, 0, 0, 0);
      aV2 = MFMA32(a, bqv2[kh*8+ks], aV2, 0, 0, 0);
    }
    if (kh == 1) {
      // o complete: bias + leaky + softmax combine -> atten slice o -> WK
      const float w2 = 1.f - w1;
      #pragma unroll
      for (int g = 0; g < 4; ++g) {
        f32x4 bb = ((const f32x4*)bv)[o*16 + mg*8 + 2*g + koct];
        s16x4 pk;
        #pragma unroll
        for (int r = 0; r < 4; ++r) {
          float va = aV1[4*g + r] + bb[r]; va = (va > 0.f) ? va : 0.01f*va;
          float vb = aV2[4*g + r] + bb[r]; vb = (vb > 0.f) ? vb : 0.01f*vb;
          pk[r] = (short)f2bf(w1*va + w2*vb);
        }
        *(s16x4*)(smem + ACT_WK + AIDX(nt*32 + l31, (o*64 + mg*32 + 8*g + 4*koct)*2)) = pk;
      }
      aV1 = zero16(); aV2 = zero16();
    }
    BARX(); p ^= 1;
  }
  return p;   // WB[p]=c11, c12 in ldA, c13 in ldB (when tails present)
}

// ---------------- K1: attention -> BN partial sums (+ X-atten store) ----------------
template<bool WRITEX>
__global__ __launch_bounds__(512) __attribute__((amdgpu_waves_per_eu(1, 2)))
void k1_attn(
    const float* __restrict__ x,
    const u16* __restrict__ wEmb16, const float* __restrict__ be,
    const float* __restrict__ bk1, const float* __restrict__ bk2,
    const u16* __restrict__ wV, const float* __restrict__ bv,
    const float* __restrict__ wrow,
    float* __restrict__ pA, float* __restrict__ pB,
    u8* __restrict__ xatt)
{
  __shared__ __align__(16) u8 smem[SMEM_BYTES];
  const int t = threadIdx.x;
  const int wt = blockIdx.x;
  const int rowbase = wt * 128;
  s16x8 ldA[2], ldB[2];

  attn_run32(smem, x, rowbase, wEmb16, be, bk1, bk2, wV, bv, wrow,
             nullptr, 0, nullptr, 0, nullptr, 0, t, ldA, ldB);

  if (WRITEX) {
    u8* dst = xatt + (size_t)wt*65536;
    #pragma unroll
    for (int j = 0; j < 8; ++j)
      *(u32x4*)(dst + j*8192 + t*16) = *(const u32x4*)(smem + ACT_WK + j*8192 + t*16);
  }

  // stats: thread t = (fg = t&63 feat-octet, cb = t>>6 col-block of 16)
  const int fg = t & 63, cb = t >> 6;
  const u8* rg = smem + ((fg & 32) ? ACT_WK : ACT_EQ);
  const int fb = (fg & 31) * 16;
  float s[8], q[8];
  #pragma unroll
  for (int e = 0; e < 8; ++e) { s[e] = 0.f; q[e] = 0.f; }
  #pragma unroll 4
  for (int c = 0; c < 16; ++c) {
    int col = cb*16 + c;
    u32x4 v = *(const u32x4*)(rg + AIDX(col, fb));
    #pragma unroll
    for (int j = 0; j < 4; ++j) {
      float a = bf2f((u16)(v[j] & 0xFFFFu));
      float b = bf2f((u16)(v[j] >> 16));
      s[2*j] += a; q[2*j] += a*a;
      s[2*j+1] += b; q[2*j+1] += b*b;
    }
  }
  float* sb = (float*)(smem + WB0_OFF);
  #pragma unroll
  for (int e = 0; e < 8; ++e) {
    sb[(fg*8 + e)*8 + cb]        = s[e];
    sb[4096 + (fg*8 + e)*8 + cb] = q[e];
  }
  __syncthreads();
  {
    int f = t;
    float ss = 0.f, qs = 0.f;
    #pragma unroll
    for (int c2 = 0; c2 < 8; ++c2) { ss += sb[f*8 + c2]; qs += sb[4096 + f*8 + c2]; }
    pA[(size_t)wt*512 + f] = ss;
    pB[(size_t)wt*512 + f] = qs;
  }
}

// ---------------- KR1 / KR2 / K2b ----------------
__global__ void kR1_reduce(const float* __restrict__ pA, const float* __restrict__ pB,
                           float* __restrict__ qA, float* __restrict__ qB)
{
  int g = blockIdx.x, t = threadIdx.x;   // 256 x 256
  float2 sA = make_float2(0.f, 0.f), sB = make_float2(0.f, 0.f);
  #pragma unroll
  for (int k = 0; k < 8; ++k) {
    size_t wg = (size_t)g*8 + k;
    float2 a = *(const float2*)(pA + wg*512 + 2*t);
    float2 b = *(const float2*)(pB + wg*512 + 2*t);
    sA.x += a.x; sA.y += a.y; sB.x += b.x; sB.y += b.y;
  }
  *(float2*)(qA + (size_t)g*512 + 2*t) = sA;
  *(float2*)(qB + (size_t)g*512 + 2*t) = sB;
}

__global__ void kR2_stats(const float* __restrict__ qA, const float* __restrict__ qB,
                          float* __restrict__ mu, float* __restrict__ rstd)
{
  int f = blockIdx.x, t = threadIdx.x;   // 512 x 256
  float s = qA[(size_t)t*512 + f];
  float q = qB[(size_t)t*512 + f];
  #pragma unroll
  for (int off = 1; off < 64; off <<= 1) {
    s += __shfl_xor(s, off);
    q += __shfl_xor(q, off);
  }
  __shared__ float ls[4], lq[4];
  if ((t & 63) == 0) { ls[t >> 6] = s; lq[t >> 6] = q; }
  __syncthreads();
  if (t == 0) {
    float S = ls[0]+ls[1]+ls[2]+ls[3];
    float Q = lq[0]+lq[1]+lq[2]+lq[3];
    float m = S * (1.f/262144.f);
    float v = Q * (1.f/262144.f) - m*m;
    mu[f] = m;
    rstd[f] = 1.f / sqrtf(v + 1e-5f);
  }
}

__global__ void k2b_fold(const float* __restrict__ W1, const float* __restrict__ b1,
                         const float* __restrict__ mu, const float* __restrict__ rstd,
                         u16* __restrict__ W1s, float* __restrict__ b1eff)
{
  int o = blockIdx.x, t = threadIdx.x;
  float local = 0.f;
  #pragma unroll
  for (int k = 0; k < 2; ++k) {
    int f = t + k*256;
    float w = W1[o*512 + f];
    float r = rstd[f];
    W1s[o*512 + f] = f2bf(w * r);
    local += w * r * mu[f];
  }
  #pragma unroll
  for (int off = 1; off < 64; off <<= 1) local += __shfl_xor(local, off);
  __shared__ float ls[4];
  if ((t & 63) == 0) ls[t >> 6] = local;
  __syncthreads();
  if (t == 0) b1eff[o] = b1[o] - (ls[0]+ls[1]+ls[2]+ls[3]);
}

// ---------------- K3: MLP (attention from X-cache or recompute) ----------------
template<bool USEX>
__global__ __launch_bounds__(512) __attribute__((amdgpu_waves_per_eu(1, 2)))
void k3_mlp(
    const float* __restrict__ x,
    const u16* __restrict__ wEmb16, const float* __restrict__ be,
    const float* __restrict__ bk1, const float* __restrict__ bk2,
    const u16* __restrict__ wV, const float* __restrict__ bv,
    const float* __restrict__ wrow,
    const u16* __restrict__ W1s, const float* __restrict__ b1eff,
    const u16* __restrict__ wW2, const float* __restrict__ b2,
    const float* __restrict__ W3, const float* __restrict__ b3,
    const u8* __restrict__ xatt,
    float* __restrict__ out)
{
  __shared__ __align__(16) u8 smem[SMEM_BYTES];
  const int t = threadIdx.x;
  const int wt = blockIdx.x;
  const int rowbase = wt * 128;
  const int lane = t & 63;
  const int l31 = lane & 31, koct = lane >> 5;
  const int wv_ = t >> 6;
  const int ng = wv_ & 3, mgw = wv_ >> 2;
  s16x8 ldA[2], ldB[2];
  int p;

  if constexpr (USEX) {
    // prologue (oldest-first): embA0, X tile, g0 -> B, g1 -> A
    s16x8 e0 = *(const s16x8*)(wEmb16 + t*8);
    s16x8 xl[8];
    const u8* xs = xatt + (size_t)wt*65536;
    #pragma unroll
    for (int j = 0; j < 8; ++j) xl[j] = *(const s16x8*)(xs + j*8192 + t*16);
    ldw_issue(W1s, 512, t, ldB);            // g0
    ldw_issue(W1s + 32768, 512, t, ldA);    // g1
    *(s16x8*)(smem + WBo(0) + EIDX2(t >> 1, (t & 1)*16)) = e0;
    BARX();
    p = 0;
    // P0: compute embA0 -> EQ; write g0 (B); issue g2 -> B; write X -> WK
    ldw_write(smem, p^1, t, ldB);           // g0
    ldw_issue(W1s + 65536, 512, t, ldB);    // g2
    {
      const float* xr = x + (size_t)(rowbase + ng*32 + l31)*39;
      embed_c32(smem + WBo(p), smem + ACT_EQ, be, make_bfr32(xr, 0, koct), ng, mgw, l31, koct);
    }
    #pragma unroll
    for (int j = 0; j < 8; ++j)
      *(s16x8*)(smem + ACT_WK + j*8192 + t*16) = xl[j];
    BARX(); p ^= 1;
  } else {
    // tails: g0 = W1s chunk0, g1 = chunk1, g2 = chunk2
    p = attn_run32(smem, x, rowbase, wEmb16, be, bk1, bk2, wV, bv, wrow,
                   W1s, 512, W1s + 32768, 512, W1s + 65536, 512, t, ldA, ldB);
  }
  // invariant: WB[p] = g0, g1 in ldA, g2 in ldB

  // GEMM1: g0..g15 = W1s(o=c&3, q=c>>2); B: q0,q1 = e_q (EQ), q2,q3 = atten (WK)
  f32x16 acc1[4];
  #pragma unroll
  for (int o = 0; o < 4; ++o) acc1[o] = zero16();
  s16x8 bq[8];

  #pragma unroll
  for (int i = 0; i < 16; ++i) {
    if ((i & 3) == 0) {
      const int areg = (i < 8) ? ACT_EQ : ACT_WK;
      const int qb = ((i >> 2) & 1) * 256;
      #pragma unroll
      for (int ks = 0; ks < 8; ++ks)
        bq[ks] = *(const s16x8*)(smem + areg + AIDX(ng*32 + l31, qb + ks*32 + koct*16));
    }
    s16x8* wset = (i & 1) ? ldB : ldA;      // g(i+1): i even -> A
    ldw_write(smem, p^1, t, wset);
    {
      const int nx = i + 3;
      if (nx < 16)      ldw_issue(W1s + (size_t)(nx&3)*32768 + (nx>>2)*128, 512, t, wset);
      else if (nx < 20) { const int j2 = nx - 16;
                          ldw_issue(wW2 + (size_t)(j2&1)*16384 + (j2>>1)*128, 256, t, wset); }
    }
    #pragma unroll
    for (int ks = 0; ks < 8; ++ks) {
      s16x8 a = *(const s16x8*)(smem + WBo(p) + WIDX(mgw*32 + l31, ks*32 + koct*16));
      acc1[i & 3] = MFMA32(a, bq[ks], acc1[i & 3], 0, 0, 0);
    }
    if (i == 15) {
      // h1 = relu(acc1 + b1eff) -> ACT_EQ
      #pragma unroll
      for (int o2 = 0; o2 < 4; ++o2)
        #pragma unroll
        for (int g = 0; g < 4; ++g) {
          f32x4 bb = ((const f32x4*)b1eff)[o2*16 + mgw*8 + 2*g + koct];
          s16x4 pk;
          #pragma unroll
          for (int r = 0; r < 4; ++r) {
            float v = acc1[o2][4*g + r] + bb[r];
            pk[r] = (short)f2bf((v > 0.f) ? v : 0.f);
          }
          *(s16x4*)(smem + ACT_EQ + AIDX(ng*32 + l31, (o2*64 + mgw*32 + 8*g + 4*koct)*2)) = pk;
        }
    }
    BARX(); p ^= 1;
  }

  // GEMM2: g16..g19 = W2(o=(c-16)&1, q=(c-16)>>1); B = h1 (EQ)
  f32x16 acc2[2];
  #pragma unroll
  for (int o = 0; o < 2; ++o) acc2[o] = zero16();

  #pragma unroll
  for (int i = 16; i < 20; ++i) {
    if (((i - 16) & 1) == 0) {
      const int qb = ((i - 16) >> 1) * 256;
      #pragma unroll
      for (int ks = 0; ks < 8; ++ks)
        bq[ks] = *(const s16x8*)(smem + ACT_EQ + AIDX(ng*32 + l31, qb + ks*32 + koct*16));
    }
    s16x8* wset = (i & 1) ? ldB : ldA;
    if (i < 19) ldw_write(smem, p^1, t, wset);
    {
      const int nx = i + 3;
      if (nx < 20) { const int j2 = nx - 16;
                     ldw_issue(wW2 + (size_t)(j2&1)*16384 + (j2>>1)*128, 256, t, wset); }
    }
    #pragma unroll
    for (int ks = 0; ks < 8; ++ks) {
      s16x8 a = *(const s16x8*)(smem + WBo(p) + WIDX(mgw*32 + l31, ks*32 + koct*16));
      acc2[(i - 16) & 1] = MFMA32(a, bq[ks], acc2[(i - 16) & 1], 0, 0, 0);
    }
    if (i == 19) {
      // h2 = relu(acc2 + b2) -> ACT_WK
      #pragma unroll
      for (int o2 = 0; o2 < 2; ++o2)
        #pragma unroll
        for (int g = 0; g < 4; ++g) {
          f32x4 bb = ((const f32x4*)b2)[o2*16 + mgw*8 + 2*g + koct];
          s16x4 pk;
          #pragma unroll
          for (int r = 0; r < 4; ++r) {
            float v = acc2[o2][4*g + r] + bb[r];
            pk[r] = (short)f2bf((v > 0.f) ? v : 0.f);
          }
          *(s16x4*)(smem + ACT_WK + AIDX(ng*32 + l31, (o2*64 + mgw*32 + 8*g + 4*koct)*2)) = pk;
        }
    }
    BARX(); p ^= 1;
  }

  // out = W3 . h2 + b3 (one thread per row)
  if (t < 128) {
    float s = b3[0];
    #pragma unroll
    for (int jj = 0; jj < 16; ++jj) {
      const u32x4 v = *(const u32x4*)(smem + ACT_WK + AIDX(t, jj*16));
      #pragma unroll
      for (int q2 = 0; q2 < 4; ++q2) {
        u32 u = v[q2];
        s += bf2f((u16)(u & 0xFFFFu)) * W3[jj*8 + q2*2];
        s += bf2f((u16)(u >> 16))     * W3[jj*8 + q2*2 + 1];
      }
    }
    out[rowbase + t] = s;
  }
}

extern "C" void kernel_launch(void* const* d_in, const int* in_sizes, int n_in,
                              void* d_out, int out_size, void* d_ws, size_t ws_size,
                              hipStream_t stream)
{
  const float* x   = (const float*)d_in[0];
  const float* We  = (const float*)d_in[1];
  const float* be  = (const float*)d_in[2];
  const float* Wk1 = (const float*)d_in[3];
  const float* bk1 = (const float*)d_in[4];
  const float* Wk2 = (const float*)d_in[5];
  const float* bk2 = (const float*)d_in[6];
  const float* Wq  = (const float*)d_in[7];
  const float* Wk  = (const float*)d_in[8];
  const float* Wv  = (const float*)d_in[9];
  const float* bv  = (const float*)d_in[10];
  const float* W1  = (const float*)d_in[11];
  const float* b1  = (const float*)d_in[12];
  const float* W2  = (const float*)d_in[13];
  const float* b2  = (const float*)d_in[14];
  const float* W3  = (const float*)d_in[15];
  const float* b3  = (const float*)d_in[16];

  u8* ws = (u8*)d_ws;
  float* pA    = (float*)(ws + PA_OFF);
  float* pB    = (float*)(ws + PB_OFF);
  float* qA    = (float*)(ws + QA_OFF);
  float* qB    = (float*)(ws + QB_OFF);
  float* mu    = (float*)(ws + MU_OFF);
  float* rstd  = (float*)(ws + RSTD_OFF);
  float* b1eff = (float*)(ws + B1E_OFF);
  u16*   wEmb  = (u16*)(ws + WEMB_OFF);
  u16*   wVb   = (u16*)(ws + WV_OFF);
  u16*   wW2   = (u16*)(ws + W2_OFF);
  u16*   wW1s  = (u16*)(ws + W1S_OFF);
  float* Wu    = (float*)(ws + WU_OFF);
  float* G     = (float*)(ws + G_OFF);
  float* g     = (float*)(ws + GG_OFF);
  float* scp   = (float*)(ws + SCP_OFF);
  float* wrow  = (float*)(ws + WROW_OFF);
  u8*    xatt  = ws + XA_OFF;

  const bool useX = (ws_size >= WS_NEED_X);

  k0_convert<<<dim3(432), dim3(256), 0, stream>>>(We, Wk1, Wk2, Wv, W2, wEmb, wVb, wW2);
  k0b_wu<<<dim3(256), dim3(256), 0, stream>>>(Wq, Wk, Wu);
  k0c_G<<<dim3(2), dim3(256), 0, stream>>>(Wu, Wk1, bk1, Wk2, bk2, G, g);
  k0d_M<<<dim3(2), dim3(256), 0, stream>>>(We, be, G, g, scp);
  k0e_scores<<<dim3(1024), dim3(256), 0, stream>>>(x, scp, wrow);
  if (useX) {
    k1_attn<true><<<dim3(NTILE), dim3(512), 0, stream>>>(x, wEmb, be, bk1, bk2, wVb, bv,
                                                         wrow, pA, pB, xatt);
  } else {
    k1_attn<false><<<dim3(NTILE), dim3(512), 0, stream>>>(x, wEmb, be, bk1, bk2, wVb, bv,
                                                          wrow, pA, pB, xatt);
  }
  kR1_reduce<<<dim3(256), dim3(256), 0, stream>>>(pA, pB, qA, qB);
  kR2_stats<<<dim3(512), dim3(256), 0, stream>>>(qA, qB, mu, rstd);
  k2b_fold<<<dim3(256), dim3(256), 0, stream>>>(W1, b1, mu, rstd, wW1s, b1eff);
  if (useX) {
    k3_mlp<true><<<dim3(NTILE), dim3(512), 0, stream>>>(x, wEmb, be, bk1, bk2, wVb, bv, wrow,
                                                        wW1s, b1eff, wW2, b2, W3, b3, xatt,
                                                        (float*)d_out);
  } else {
    k3_mlp<false><<<dim3(NTILE), dim3(512), 0, stream>>>(x, wEmb, be, bk1, bk2, wVb, bv, wrow,
                                                         wW1s, b1eff, wW2, b2, W3, b3, xatt,
                                                         (float*)d_out);
  }
}